// Round 1
// baseline (264.848 us; speedup 1.0000x reference)
//
#include <hip/hip_runtime.h>

// LIF repeat-encoder:
//   in  [B=64, C=64, L=512] fp32
//   out [B=64, T=32, L=512, C=64] fp32 (spikes, 0.0 or 1.0)
// Per element x = in[b,c,l], independent scalar recurrence over T steps:
//   v = v + (x - v)/2 ; s = (v >= 1) ; v = v*(1-s)
//
// Memory-bound: 8 MB read + 256 MB write => ~42 us floor at 6.3 TB/s.
// Layout: one thread handles (b, l, 4 consecutive c) -> float4 stores;
// a wave's 64 lanes cover (4 l values x all 64 c) = contiguous 1 KiB per t.
// NUMERICS: must match reference rounding exactly (spike flip = absmax 1.0):
// keep v + (x - v)*0.5f (the *0.5 is exact; FMA contraction rounds the same).

constexpr int B = 64;
constexpr int C = 64;
constexpr int L = 512;
constexpr int T = 32;

__global__ __launch_bounds__(256) void lif_repeat_kernel(
    const float* __restrict__ in, float* __restrict__ out) {
  const int g = blockIdx.x * blockDim.x + threadIdx.x;  // [0, B*L*C/4)
  const int c4 = g & 15;          // C/4 = 16 groups of 4 channels
  const int l  = (g >> 4) & 511;  // L = 512
  const int b  = g >> 13;         // 4 + 9 bits
  const int c  = c4 * 4;

  // Input: in[b*C*L + c*L + l], channel stride = L floats.
  const float* ip = in + (size_t)b * (C * L) + (size_t)c * L + l;
  const float x0 = ip[0 * L];
  const float x1 = ip[1 * L];
  const float x2 = ip[2 * L];
  const float x3 = ip[3 * L];

  // Output: out[b*T*L*C + t*L*C + l*C + c], as float4 units.
  float4* op = (float4*)(out + (size_t)b * (T * L * C) + (size_t)l * C + c);
  constexpr int t_stride4 = (L * C) / 4;  // 8192 float4 per time step

  float v0 = 0.f, v1 = 0.f, v2 = 0.f, v3 = 0.f;
#pragma unroll
  for (int t = 0; t < T; ++t) {
    v0 += (x0 - v0) * 0.5f;
    v1 += (x1 - v1) * 0.5f;
    v2 += (x2 - v2) * 0.5f;
    v3 += (x3 - v3) * 0.5f;
    const float s0 = (v0 >= 1.0f) ? 1.0f : 0.0f;
    const float s1 = (v1 >= 1.0f) ? 1.0f : 0.0f;
    const float s2 = (v2 >= 1.0f) ? 1.0f : 0.0f;
    const float s3 = (v3 >= 1.0f) ? 1.0f : 0.0f;
    op[(size_t)t * t_stride4] = make_float4(s0, s1, s2, s3);
    // hard reset (exactly v*(1-s): s==1 -> 0, s==0 -> v)
    v0 = (s0 != 0.0f) ? 0.0f : v0;
    v1 = (s1 != 0.0f) ? 0.0f : v1;
    v2 = (s2 != 0.0f) ? 0.0f : v2;
    v3 = (s3 != 0.0f) ? 0.0f : v3;
  }
}

extern "C" void kernel_launch(void* const* d_in, const int* in_sizes, int n_in,
                              void* d_out, int out_size, void* d_ws, size_t ws_size,
                              hipStream_t stream) {
  const float* in = (const float*)d_in[0];
  float* out = (float*)d_out;
  const int n_threads = (B * L * C) / 4;       // 524288
  const int block = 256;
  const int grid = n_threads / block;          // 2048
  lif_repeat_kernel<<<grid, block, 0, stream>>>(in, out);
}